// Round 1
// baseline (537.928 us; speedup 1.0000x reference)
//
#include <hip/hip_runtime.h>
#include <hip/hip_bf16.h>

// B=8, R=8, N=1024, D_IN=D_OUT=256, all fp32 in/out.
// Stage 1: support_t[b,r,e,n] = bf16(sum_d W[r,d,e]*x[b,n,d] + bias[r,e])  (ws, 32 MB)
// Stage 2: out[b,m,e] += adj[b,r,m,n]*support_t[b,r,e,n]  (bf16 MFMA, split-K=4, atomicAdd)
// Stage 3: ReLU in-place.

#define Bb 8
#define Rr 8
#define Nn 1024
#define Dd 256

typedef __attribute__((ext_vector_type(8))) short short8;
typedef __attribute__((ext_vector_type(4))) short short4v;
typedef __attribute__((ext_vector_type(4))) float f32x4;

__device__ __forceinline__ short f2bf(float f) {
    unsigned u = __builtin_bit_cast(unsigned, f);
    u += 0x7fffu + ((u >> 16) & 1u);   // RNE
    return (short)(u >> 16);
}

// ---------------- Stage 1: support_t = (W^T x^T) + bias, bf16 ----------------
// grid (2 e-tiles, 8 n-tiles, 64 b*r), block 256 = 4 waves (2e x 2n), tile 128e x 128n, K=256.
__global__ __launch_bounds__(256, 2) void support_kernel(
        const float* __restrict__ x, const float* __restrict__ W,
        const float* __restrict__ bias, short* __restrict__ sup) {
    __shared__ short As[128][40];  // [e_local][d_local]  (W^T tile; +8 pad -> frag reads 2-way free)
    __shared__ short Bs[128][40];  // [n_local][d_local]  (x tile, natural layout)

    const int tid = threadIdx.x;
    const int e_t = blockIdx.x;            // 0..1
    const int n_t = blockIdx.y;            // 0..7
    const int br  = blockIdx.z;            // 0..63
    const int b   = br >> 3, r = br & 7;

    const int wave = tid >> 6, lane = tid & 63;
    const int quad = lane >> 4, l16 = lane & 15;
    const int we = wave & 1, wn = wave >> 1;

    f32x4 acc[4][4] = {};

    const float* Wr = W + r * Dd * Dd;
    const float* xb = x + ((size_t)b * Nn + n_t * 128) * Dd;

    for (int d0 = 0; d0 < Dd; d0 += 32) {
        // A tile: W^T -> As[e][d]. Source W[r][d][e], e contiguous; transpose via scattered u16.
        #pragma unroll
        for (int i = 0; i < 4; ++i) {
            int idx = tid + i * 256;          // 0..1023 float4s over 32d x 128e
            int d_l = idx >> 5;               // 0..31
            int e_l = (idx & 31) * 4;         // 0..124
            f32x4 v = *(const f32x4*)(Wr + (d0 + d_l) * Dd + e_t * 128 + e_l);
            As[e_l + 0][d_l] = f2bf(v[0]);
            As[e_l + 1][d_l] = f2bf(v[1]);
            As[e_l + 2][d_l] = f2bf(v[2]);
            As[e_l + 3][d_l] = f2bf(v[3]);
        }
        // B tile: x -> Bs[n][d], natural (d contiguous).
        #pragma unroll
        for (int i = 0; i < 4; ++i) {
            int idx = tid + i * 256;
            int n_l = idx >> 3;               // 0..127
            int d4  = (idx & 7) * 4;          // 0..28
            f32x4 v = *(const f32x4*)(xb + n_l * Dd + d0 + d4);
            short4v s;
            s[0] = f2bf(v[0]); s[1] = f2bf(v[1]); s[2] = f2bf(v[2]); s[3] = f2bf(v[3]);
            *(short4v*)&Bs[n_l][d4] = s;
        }
        __syncthreads();
        short8 a[4], bf[4];
        #pragma unroll
        for (int i = 0; i < 4; ++i)
            a[i] = *(const short8*)&As[we * 64 + i * 16 + l16][quad * 8];
        #pragma unroll
        for (int j = 0; j < 4; ++j)
            bf[j] = *(const short8*)&Bs[wn * 64 + j * 16 + l16][quad * 8];
        #pragma unroll
        for (int i = 0; i < 4; ++i)
            #pragma unroll
            for (int j = 0; j < 4; ++j)
                acc[i][j] = __builtin_amdgcn_mfma_f32_16x16x32_bf16(a[i], bf[j], acc[i][j], 0, 0, 0);
        __syncthreads();
    }

    // Epilogue: C[row=e][col=n]; add bias[r][e]; store bf16 to sup[(b,r),e,n].
    #pragma unroll
    for (int i = 0; i < 4; ++i) {
        #pragma unroll
        for (int reg = 0; reg < 4; ++reg) {
            int e = e_t * 128 + we * 64 + i * 16 + quad * 4 + reg;
            float bv = bias[r * Dd + e];
            #pragma unroll
            for (int j = 0; j < 4; ++j) {
                int n = n_t * 128 + wn * 64 + j * 16 + l16;
                sup[(((b * Rr + r) * Dd + e) << 10) + n] = f2bf(acc[i][j][reg] + bv);
            }
        }
    }
}

// ---------------- Stage 2: out += adj @ support_t^T (bf16 MFMA, split-K) ----------------
// grid.x = e2 + 2*ks (8), grid.y = m-tile (8), grid.z = b (8) -> 512 blocks.
// block 256 = 4 waves (2m x 2e), tile 128m x 128e, K-chunk = 2048 (2 relations), BK=32.
__global__ __launch_bounds__(256, 2) void gcn_gemm_kernel(
        const float* __restrict__ adj, const short* __restrict__ sup,
        float* __restrict__ out) {
    __shared__ short Aa[128][40];  // [m][k]  adj tile (fp32 -> bf16 on the fly)
    __shared__ short Bs[128][40];  // [e][k]  support_t tile (already bf16)

    const int tid = threadIdx.x;
    const int e2  = blockIdx.x & 1;        // e-tile 0..1
    const int ks  = blockIdx.x >> 1;       // K-split 0..3
    const int m_t = blockIdx.y;            // 0..7
    const int b   = blockIdx.z;            // 0..7

    const int wave = tid >> 6, lane = tid & 63;
    const int quad = lane >> 4, l16 = lane & 15;
    const int wm = wave >> 1, we = wave & 1;

    f32x4 acc[4][4] = {};

    for (int it = 0; it < 64; ++it) {
        const int kk = ks * 2048 + it * 32;
        const int r  = kk >> 10;
        const int n0 = kk & 1023;

        const float* ap = adj + ((size_t)((b * Rr + r) * Nn + m_t * 128)) * Nn + n0;
        #pragma unroll
        for (int i = 0; i < 4; ++i) {
            int idx = tid + i * 256;          // 1024 float4s over 128m x 32k
            int m_l = idx >> 3;
            int k4  = (idx & 7) * 4;
            f32x4 v = *(const f32x4*)(ap + (size_t)m_l * Nn + k4);
            short4v s;
            s[0] = f2bf(v[0]); s[1] = f2bf(v[1]); s[2] = f2bf(v[2]); s[3] = f2bf(v[3]);
            *(short4v*)&Aa[m_l][k4] = s;
        }
        const short* bp = sup + (((size_t)((b * Rr + r) * Dd + e2 * 128)) << 10) + n0;
        #pragma unroll
        for (int i = 0; i < 2; ++i) {
            int idx = tid + i * 256;          // 512 16B loads over 128e x 32k
            int e_l = idx >> 2;
            int k8  = (idx & 3) * 8;
            short8 v = *(const short8*)(bp + ((size_t)e_l << 10) + k8);
            *(short8*)&Bs[e_l][k8] = v;
        }
        __syncthreads();
        short8 a[4], bf[4];
        #pragma unroll
        for (int i = 0; i < 4; ++i)
            a[i] = *(const short8*)&Aa[wm * 64 + i * 16 + l16][quad * 8];
        #pragma unroll
        for (int j = 0; j < 4; ++j)
            bf[j] = *(const short8*)&Bs[we * 64 + j * 16 + l16][quad * 8];
        #pragma unroll
        for (int i = 0; i < 4; ++i)
            #pragma unroll
            for (int j = 0; j < 4; ++j)
                acc[i][j] = __builtin_amdgcn_mfma_f32_16x16x32_bf16(a[i], bf[j], acc[i][j], 0, 0, 0);
        __syncthreads();
    }

    // Epilogue: C[row=m][col=e]; split-K partial -> atomicAdd into zeroed out.
    float* ob = out + ((size_t)b * Nn + m_t * 128) * Dd + e2 * 128;
    #pragma unroll
    for (int i = 0; i < 4; ++i)
        #pragma unroll
        for (int reg = 0; reg < 4; ++reg) {
            int m_l = wm * 64 + i * 16 + quad * 4 + reg;
            #pragma unroll
            for (int j = 0; j < 4; ++j) {
                int e_l = we * 64 + j * 16 + l16;
                atomicAdd(ob + (size_t)m_l * Dd + e_l, acc[i][j][reg]);
            }
        }
}

// ---------------- Stage 3: ReLU in place ----------------
__global__ void relu_kernel(float* __restrict__ out, int n4) {
    int i = blockIdx.x * blockDim.x + threadIdx.x;
    if (i < n4) {
        f32x4* p = (f32x4*)out;
        f32x4 v = p[i];
        v[0] = fmaxf(v[0], 0.f); v[1] = fmaxf(v[1], 0.f);
        v[2] = fmaxf(v[2], 0.f); v[3] = fmaxf(v[3], 0.f);
        p[i] = v;
    }
}

extern "C" void kernel_launch(void* const* d_in, const int* in_sizes, int n_in,
                              void* d_out, int out_size, void* d_ws, size_t ws_size,
                              hipStream_t stream) {
    const float* x    = (const float*)d_in[0];
    const float* adj  = (const float*)d_in[1];
    const float* W    = (const float*)d_in[2];
    const float* bias = (const float*)d_in[3];
    float* out = (float*)d_out;
    short* sup = (short*)d_ws;   // needs 8*8*256*1024*2 = 32 MB of ws

    hipMemsetAsync(d_out, 0, (size_t)out_size * sizeof(float), stream);
    support_kernel<<<dim3(2, 8, 64), 256, 0, stream>>>(x, W, bias, sup);
    gcn_gemm_kernel<<<dim3(8, 8, 8), 256, 0, stream>>>(adj, sup, out);
    relu_kernel<<<(out_size / 4 + 255) / 256, 256, 0, stream>>>(out, out_size / 4);
}

// Round 2
// 464.694 us; speedup vs baseline: 1.1576x; 1.1576x over previous
//
#include <hip/hip_runtime.h>
#include <hip/hip_bf16.h>

// B=8, R=8, N=1024, D_IN=D_OUT=256, all fp32 in/out.
// prep_w : Wt[r][e][d] = bf16(W[r][d][e])        (scratch: first 1 MB of d_out, pre-memset)
// stage 1: sup[b,r,e,n] = bf16(x@W + bias)        (ws, 32 MB)
// stage 2: out[b,m,e] += adj[b,r,m,n]*sup[b,r,e,n] (bf16 MFMA, split-K=8, atomicAdd)
// stage 3: ReLU in place.

#define Bb 8
#define Rr 8
#define Nn 1024
#define Dd 256

typedef __attribute__((ext_vector_type(8))) short short8;
typedef __attribute__((ext_vector_type(4))) short short4v;
typedef __attribute__((ext_vector_type(4))) float f32x4;

__device__ __forceinline__ short f2bf(float f) {
    unsigned u = __builtin_bit_cast(unsigned, f);
    u += 0x7fffu + ((u >> 16) & 1u);   // RNE
    return (short)(u >> 16);
}

// ---------------- prep: Wt[r][e][d] bf16 <- W[r][d][e] f32 ----------------
// grid (4 e-tiles, 4 d-tiles, 8 r), 64x64 tiles, LDS transpose.
__global__ void prep_w_kernel(const float* __restrict__ W, short* __restrict__ Wt) {
    __shared__ short T[64][72];
    const int tid = threadIdx.x;
    const int et = blockIdx.x, dt = blockIdx.y, r = blockIdx.z;
    const float* Wr = W + ((size_t)r * Dd + dt * 64) * Dd + et * 64;
    #pragma unroll
    for (int i = 0; i < 4; ++i) {
        int idx = tid + i * 256;          // 1024 f32x4 over 64d x 16(e/4)
        int d_l = idx >> 4;
        int e4  = (idx & 15) * 4;
        f32x4 v = *(const f32x4*)(Wr + d_l * Dd + e4);
        T[e4 + 0][d_l] = f2bf(v[0]);
        T[e4 + 1][d_l] = f2bf(v[1]);
        T[e4 + 2][d_l] = f2bf(v[2]);
        T[e4 + 3][d_l] = f2bf(v[3]);
    }
    __syncthreads();
    short* o = Wt + ((size_t)r * Dd + et * 64) * Dd + dt * 64;
    #pragma unroll
    for (int i = 0; i < 2; ++i) {
        int idx = tid + i * 256;          // 512 short8 over 64e x 8(d/8)
        int e_l = idx >> 3;
        int d8  = (idx & 7) * 8;
        *(short8*)(o + e_l * Dd + d8) = *(const short8*)&T[e_l][d8];
    }
}

// ---------------- Stage 1: sup = (Wt @ x^T) + bias, bf16 ----------------
// grid (2 e-tiles, 8 n-tiles, 64 b*r), block 256 = 4 waves (2e x 2n), tile 128e x 128n, K=256.
__global__ __launch_bounds__(256) void support_kernel(
        const float* __restrict__ x, const short* __restrict__ Wt,
        const float* __restrict__ bias, short* __restrict__ sup) {
    __shared__ short As[128][40];  // [e][d]  Wt tile (bf16, clean vector copy)
    __shared__ short Bs[128][40];  // [n][d]  x tile (fp32 -> bf16)

    const int tid = threadIdx.x;
    const int e_t = blockIdx.x, n_t = blockIdx.y, br = blockIdx.z;
    const int b = br >> 3, r = br & 7;
    const int wave = tid >> 6, lane = tid & 63;
    const int quad = lane >> 4, l16 = lane & 15;
    const int we = wave & 1, wn = wave >> 1;

    const short* wp = Wt + ((size_t)r * Dd + e_t * 128) * Dd;
    const float* xb = x + ((size_t)b * Nn + n_t * 128) * Dd;

    short8 aw[2];
    f32x4 xv[4];
    auto load = [&](int d0) {
        #pragma unroll
        for (int i = 0; i < 2; ++i) {
            int idx = tid + i * 256;
            aw[i] = *(const short8*)(wp + (idx >> 2) * Dd + d0 + (idx & 3) * 8);
        }
        #pragma unroll
        for (int i = 0; i < 4; ++i) {
            int idx = tid + i * 256;
            xv[i] = *(const f32x4*)(xb + (idx >> 3) * Dd + d0 + (idx & 7) * 4);
        }
    };

    f32x4 acc[4][4] = {};
    load(0);
    for (int it = 0; it < 8; ++it) {
        #pragma unroll
        for (int i = 0; i < 2; ++i) {
            int idx = tid + i * 256;
            *(short8*)&As[idx >> 2][(idx & 3) * 8] = aw[i];
        }
        #pragma unroll
        for (int i = 0; i < 4; ++i) {
            int idx = tid + i * 256;
            short4v s;
            s[0] = f2bf(xv[i][0]); s[1] = f2bf(xv[i][1]);
            s[2] = f2bf(xv[i][2]); s[3] = f2bf(xv[i][3]);
            *(short4v*)&Bs[idx >> 3][(idx & 7) * 4] = s;
        }
        if (it < 7) load((it + 1) * 32);
        __syncthreads();
        short8 a[4], bfr[4];
        #pragma unroll
        for (int i = 0; i < 4; ++i)
            a[i] = *(const short8*)&As[we * 64 + i * 16 + l16][quad * 8];
        #pragma unroll
        for (int j = 0; j < 4; ++j)
            bfr[j] = *(const short8*)&Bs[wn * 64 + j * 16 + l16][quad * 8];
        #pragma unroll
        for (int i = 0; i < 4; ++i)
            #pragma unroll
            for (int j = 0; j < 4; ++j)
                acc[i][j] = __builtin_amdgcn_mfma_f32_16x16x32_bf16(a[i], bfr[j], acc[i][j], 0, 0, 0);
        __syncthreads();
    }

    // Epilogue: C[row=e][col=n]; add bias[r][e]; bf16 store to sup[(b,r),e,n].
    #pragma unroll
    for (int i = 0; i < 4; ++i)
        #pragma unroll
        for (int reg = 0; reg < 4; ++reg) {
            int e = e_t * 128 + we * 64 + i * 16 + quad * 4 + reg;
            float bv = bias[r * Dd + e];
            #pragma unroll
            for (int j = 0; j < 4; ++j) {
                int n = n_t * 128 + wn * 64 + j * 16 + l16;
                sup[(((b * Rr + r) * Dd + e) << 10) + n] = f2bf(acc[i][j][reg] + bv);
            }
        }
}

// ---------------- Stage 2: out += adj @ sup^T (bf16 MFMA, split-K=8) ----------------
// grid.x = e2 + 2*ks (16), grid.y = m-tile (8), grid.z = b (8) -> 1024 blocks.
// block 256 = 4 waves (2m x 2e), tile 128m x 128e, K-chunk = 1024 (one relation), BK=32.
__global__ __launch_bounds__(256) void gcn_gemm_kernel(
        const float* __restrict__ adj, const short* __restrict__ sup,
        float* __restrict__ out) {
    __shared__ short Aa[128][40];  // [m][k]  adj tile (fp32 -> bf16)
    __shared__ short Bs[128][40];  // [e][k]  sup tile (already bf16)

    const int tid = threadIdx.x;
    const int e2  = blockIdx.x & 1;
    const int r   = blockIdx.x >> 1;       // K-split: one relation per block
    const int m_t = blockIdx.y, b = blockIdx.z;
    const int wave = tid >> 6, lane = tid & 63;
    const int quad = lane >> 4, l16 = lane & 15;
    const int wm = wave >> 1, we = wave & 1;

    const float* ap = adj + ((size_t)((b * Rr + r) * Nn + m_t * 128)) * Nn;
    const short* bp = sup + (((size_t)((b * Rr + r) * Dd + e2 * 128)) << 10);

    f32x4 av[4];
    short8 bv[2];
    auto load = [&](int n0) {
        #pragma unroll
        for (int i = 0; i < 4; ++i) {
            int idx = tid + i * 256;          // 1024 f32x4 over 128m x 8(k/4)
            av[i] = *(const f32x4*)(ap + (size_t)(idx >> 3) * Nn + n0 + (idx & 7) * 4);
        }
        #pragma unroll
        for (int i = 0; i < 2; ++i) {
            int idx = tid + i * 256;          // 512 short8 over 128e x 4(k/8)
            bv[i] = *(const short8*)(bp + ((size_t)(idx >> 2) << 10) + n0 + (idx & 3) * 8);
        }
    };

    f32x4 acc[4][4] = {};
    load(0);
    for (int it = 0; it < 32; ++it) {
        #pragma unroll
        for (int i = 0; i < 4; ++i) {
            int idx = tid + i * 256;
            short4v s;
            s[0] = f2bf(av[i][0]); s[1] = f2bf(av[i][1]);
            s[2] = f2bf(av[i][2]); s[3] = f2bf(av[i][3]);
            *(short4v*)&Aa[idx >> 3][(idx & 7) * 4] = s;
        }
        #pragma unroll
        for (int i = 0; i < 2; ++i) {
            int idx = tid + i * 256;
            *(short8*)&Bs[idx >> 2][(idx & 3) * 8] = bv[i];
        }
        if (it < 31) load((it + 1) * 32);     // prefetch flies during barrier + MFMA
        __syncthreads();
        short8 a[4], bfr[4];
        #pragma unroll
        for (int i = 0; i < 4; ++i)
            a[i] = *(const short8*)&Aa[wm * 64 + i * 16 + l16][quad * 8];
        #pragma unroll
        for (int j = 0; j < 4; ++j)
            bfr[j] = *(const short8*)&Bs[we * 64 + j * 16 + l16][quad * 8];
        #pragma unroll
        for (int i = 0; i < 4; ++i)
            #pragma unroll
            for (int j = 0; j < 4; ++j)
                acc[i][j] = __builtin_amdgcn_mfma_f32_16x16x32_bf16(a[i], bfr[j], acc[i][j], 0, 0, 0);
        __syncthreads();
    }

    // Epilogue: C[row=m][col=e]; split-K partial -> atomicAdd into zeroed out.
    float* ob = out + ((size_t)b * Nn + m_t * 128) * Dd + e2 * 128;
    #pragma unroll
    for (int i = 0; i < 4; ++i)
        #pragma unroll
        for (int reg = 0; reg < 4; ++reg) {
            int m_l = wm * 64 + i * 16 + quad * 4 + reg;
            #pragma unroll
            for (int j = 0; j < 4; ++j) {
                int e_l = we * 64 + j * 16 + l16;
                atomicAdd(ob + (size_t)m_l * Dd + e_l, acc[i][j][reg]);
            }
        }
}

// ---------------- Stage 3: ReLU in place ----------------
__global__ void relu_kernel(float* __restrict__ out, int n4) {
    int i = blockIdx.x * blockDim.x + threadIdx.x;
    if (i < n4) {
        f32x4* p = (f32x4*)out;
        f32x4 v = p[i];
        v[0] = fmaxf(v[0], 0.f); v[1] = fmaxf(v[1], 0.f);
        v[2] = fmaxf(v[2], 0.f); v[3] = fmaxf(v[3], 0.f);
        p[i] = v;
    }
}

extern "C" void kernel_launch(void* const* d_in, const int* in_sizes, int n_in,
                              void* d_out, int out_size, void* d_ws, size_t ws_size,
                              hipStream_t stream) {
    const float* x    = (const float*)d_in[0];
    const float* adj  = (const float*)d_in[1];
    const float* W    = (const float*)d_in[2];
    const float* bias = (const float*)d_in[3];
    float* out = (float*)d_out;
    short* sup = (short*)d_ws;            // 32 MB of ws (proven to fit)
    short* Wt  = (short*)d_out;           // 1 MB scratch inside d_out, consumed before memset

    prep_w_kernel<<<dim3(4, 4, 8), 256, 0, stream>>>(W, Wt);
    support_kernel<<<dim3(2, 8, 64), 256, 0, stream>>>(x, Wt, bias, sup);
    hipMemsetAsync(d_out, 0, (size_t)out_size * sizeof(float), stream);
    gcn_gemm_kernel<<<dim3(16, 8, 8), 256, 0, stream>>>(adj, sup, out);
    relu_kernel<<<(out_size / 4 + 255) / 256, 256, 0, stream>>>(out, out_size / 4);
}